// Round 10
// baseline (187.426 us; speedup 1.0000x reference)
//
#include <hip/hip_runtime.h>
#include <math.h>

#define N_TOPK 6000
#define POST_K 1000
#define WORDS 94            // ceil(6000/64)
#define MT_STRIDE 6016      // padded row count for transposed mask (94*64)
#define SEL_CAP 16384       // n ~= 6002 with 26-bit threshold; 2.7x headroom
#define RANK_JT 1024
#define NMS_THRESH 0.7f
#define HPAD 16             // one counter per 64B cacheline
#define NBIN 8192           // 13-bit bins
#define BSHIFT1 19          // key >> 19 = top-13-bit bin
#define BSHIFT2 6           // (key >> 6) & 8191 = next-13-bit sub-bin

struct Hdr {
  unsigned int hist1[NBIN*HPAD];
  unsigned int hist2[NBIN*HPAD];
  unsigned int binB;             // pick1 result: top-13-bit boundary bin
  unsigned int kth;              // remaining rank within bin B
  unsigned int thr;              // pick2 result: 26-bit selection threshold
  unsigned int selCount;
};

// ---- shared decode core (must match reference numerics; _rn blocks FMA) ----
__device__ __forceinline__ void decode_core(
    float a0, float a1, float a2, float a3,
    float d0, float d1, float d2, float d3,
    float H, float W,
    float& x1, float& y1, float& x2, float& y2, bool& valid)
{
  float aw = __fsub_rn(a2, a0);
  float ah = __fsub_rn(a3, a1);
  float ax = __fadd_rn(a0, __fmul_rn(0.5f, aw));
  float ay = __fadd_rn(a1, __fmul_rn(0.5f, ah));
  float px = __fadd_rn(ax, __fmul_rn(d0, aw));
  float py = __fadd_rn(ay, __fmul_rn(d1, ah));
  float c2 = fminf(fmaxf(d2, -10.0f), 10.0f);
  float c3 = fminf(fmaxf(d3, -10.0f), 10.0f);
  // correctly-rounded f32 exp via double (central w.r.t. any 1-ulp reference exp)
  float pw = __fmul_rn(aw, (float)exp((double)c2));
  float ph = __fmul_rn(ah, (float)exp((double)c3));
  float Wm = __fsub_rn(W, 1.0f);
  float Hm = __fsub_rn(H, 1.0f);
  float hw = __fmul_rn(0.5f, pw);
  float hh = __fmul_rn(0.5f, ph);
  x1 = fminf(fmaxf(__fsub_rn(px, hw), 0.0f), Wm);
  y1 = fminf(fmaxf(__fsub_rn(py, hh), 0.0f), Hm);
  x2 = fminf(fmaxf(__fadd_rn(px, hw), 0.0f), Wm);
  y2 = fminf(fmaxf(__fadd_rn(py, hh), 0.0f), Hm);
  valid = (__fsub_rn(x2, x1) >= 16.0f) && (__fsub_rn(y2, y1) >= 16.0f);
}

// ---- init: zero hist1/hist2/rank/counters ----
__global__ void __launch_bounds__(256) k_init(Hdr* h, unsigned int* rank){
  int tid = blockIdx.x*256 + threadIdx.x;
  int stride = gridDim.x*256;
  for (int i = tid; i < NBIN*HPAD; i += stride){ h->hist1[i] = 0; h->hist2[i] = 0; }
  for (int i = tid; i < SEL_CAP; i += stride) rank[i] = 0;
  if (tid == 0){ h->binB = 0; h->kth = 0; h->thr = 0; h->selCount = 0; }
}

// ---- stage 1: decode + score -> monotone u32 key; fused 13-bit LDS histogram.
//  4 independent element-chains per thread (block-strided) so the compiler
//  interleaves the exp(double) dependency chains (ILP vs latency-bound R9). ----
__global__ void __launch_bounds__(256) k_decode(const int* __restrict__ bidx,
    const int* __restrict__ isz, const float4* __restrict__ anc4,
    const float* __restrict__ logits, const float4* __restrict__ del4,
    unsigned int* __restrict__ u, int N, Hdr* __restrict__ h)
{
  __shared__ unsigned int lh[NBIN];
  for (int b = threadIdx.x; b < NBIN; b += 256) lh[b] = 0;
  __syncthreads();
  const int T = gridDim.x * blockDim.x;
  const int tid = blockIdx.x*blockDim.x + threadIdx.x;
  for (int base = tid; base < N; base += 4*T){
    bool in[4]; int ii[4]; float4 a[4], d[4]; float lg[4]; int bb[4];
    #pragma unroll
    for (int j = 0; j < 4; ++j){
      ii[j] = base + j*T;
      in[j] = ii[j] < N;
      int i = in[j] ? ii[j] : 0;
      a[j] = anc4[i];
      d[j] = del4[i];
      lg[j] = logits[i];
      bb[j] = bidx[i];
    }
    float Hh[4], Ww[4];
    #pragma unroll
    for (int j = 0; j < 4; ++j){
      Hh[j] = (float)isz[bb[j]*2+0];
      Ww[j] = (float)isz[bb[j]*2+1];
    }
    unsigned int key[4];
    #pragma unroll
    for (int j = 0; j < 4; ++j){
      float x1,y1,x2,y2; bool valid;
      decode_core(a[j].x,a[j].y,a[j].z,a[j].w, d[j].x,d[j].y,d[j].z,d[j].w,
                  Hh[j], Ww[j], x1,y1,x2,y2, valid);
      float s;
      if (valid){
        float e = (float)exp(-(double)lg[j]);     // exp-form sigmoid (XLA logistic expander)
        s = __fdiv_rn(1.0f, __fadd_rn(1.0f, e));
      } else {
        s = -__builtin_inff();
      }
      unsigned int w = __float_as_uint(s);
      key[j] = (w & 0x80000000u) ? ~w : (w | 0x80000000u);
    }
    #pragma unroll
    for (int j = 0; j < 4; ++j){
      if (in[j]){
        u[ii[j]] = key[j];
        atomicAdd(&lh[key[j] >> BSHIFT1], 1u);
      }
    }
  }
  __syncthreads();
  for (int b = threadIdx.x; b < NBIN; b += 256){
    unsigned int c = lh[b];
    if (c) atomicAdd(&h->hist1[(size_t)b*HPAD], c);   // skip-zero, padded lines
  }
}

// ---- pick over 8192 bins (suffix scan). phase 0: hist1 -> binB,kth.
//      phase 1: hist2 -> thr = (binB<<19)|(S<<6). ----
__global__ void __launch_bounds__(256) k_pick(Hdr* h, int phase){
  __shared__ unsigned int A[256];
  const int t = threadIdx.x;
  const unsigned int* hist = phase ? h->hist2 : h->hist1;
  unsigned int target = phase ? h->kth : N_TOPK;
  unsigned int loc[32];
  unsigned int L = 0;
  #pragma unroll
  for (int r = 0; r < 32; ++r){
    loc[r] = hist[(size_t)(t*32 + r)*HPAD];
    L += loc[r];
  }
  A[t] = L;
  __syncthreads();
  // inclusive suffix scan: A[t] = sum_{j>=t} L_j
  for (int d = 1; d < 256; d <<= 1){
    unsigned int v = A[t];
    if (t + d < 256) v += A[t + d];
    __syncthreads();
    A[t] = v;
    __syncthreads();
  }
  unsigned int suf = A[t];
  unsigned int sufNext = (t < 255) ? A[t+1] : 0;
  if (suf >= target && sufNext < target){   // exactly one thread
    unsigned int acc = sufNext;
    int bb = t*32;
    #pragma unroll
    for (int r = 31; r >= 0; --r){
      acc += loc[r];
      if (acc >= target){ bb = t*32 + r; acc -= loc[r]; break; }
    }
    if (phase == 0){
      h->binB = (unsigned int)bb;
      h->kth = target - acc;     // remaining rank within bin bb (1..count(bb))
    } else {
      h->thr = (h->binB << BSHIFT1) | ((unsigned int)bb << BSHIFT2);
    }
  }
}

// ---- second-level histogram: keys in bin B, next 13 bits; global padded atomics ----
__global__ void __launch_bounds__(256) k_hist2(const uint4* __restrict__ u4, int N4,
                                               Hdr* __restrict__ h){
  unsigned int B = h->binB;
  int stride = gridDim.x*blockDim.x;
  for (int i = blockIdx.x*blockDim.x + threadIdx.x; i < N4; i += stride){
    uint4 v = u4[i];
    #pragma unroll
    for (int kcomp = 0; kcomp < 4; ++kcomp){
      unsigned int vv = (kcomp==0)?v.x:(kcomp==1)?v.y:(kcomp==2)?v.z:v.w;
      if ((vv >> BSHIFT1) == B)
        atomicAdd(&h->hist2[(size_t)((vv >> BSHIFT2) & (NBIN-1))*HPAD], 1u);
    }
  }
}

// ---- compact all u >= thr (n ~= 6002 << SEL_CAP); block-aggregated allocation ----
__global__ void __launch_bounds__(256) k_compact(const uint4* __restrict__ u4, int N4,
                                                 Hdr* __restrict__ h,
                                                 unsigned long long* __restrict__ sel){
  __shared__ unsigned long long lbuf[1024];
  __shared__ unsigned int lcnt, lbase;
  if (threadIdx.x == 0) lcnt = 0;
  __syncthreads();
  unsigned int thr = h->thr;
  int stride = gridDim.x*blockDim.x;
  for (int i = blockIdx.x*blockDim.x + threadIdx.x; i < N4; i += stride){
    uint4 v = u4[i];
    unsigned int base = (unsigned int)i * 4u;
    #pragma unroll
    for (int kcomp = 0; kcomp < 4; ++kcomp){
      unsigned int vv = (kcomp==0)?v.x:(kcomp==1)?v.y:(kcomp==2)?v.z:v.w;
      if (vv >= thr){
        unsigned long long key = ((unsigned long long)vv << 32)
                               | (unsigned long long)(0xFFFFFFFFu - (base + kcomp));
        unsigned int p = atomicAdd(&lcnt, 1u);
        if (p < 1024){
          lbuf[p] = key;
        } else {                                   // overflow fallback
          unsigned int gp = atomicAdd(&h->selCount, 1u);
          if (gp < SEL_CAP) sel[gp] = key;
        }
      }
    }
  }
  __syncthreads();
  unsigned int n = lcnt; if (n > 1024) n = 1024;
  if (threadIdx.x == 0 && n) lbase = atomicAdd(&h->selCount, n);
  __syncthreads();
  if (n){
    unsigned int base = lbase;
    for (unsigned int kk = threadIdx.x; kk < n; kk += 256){
      unsigned int p = base + kk;
      if (p < SEL_CAP) sel[p] = lbuf[kk];
    }
  }
}

// ---- rank: rank_i = #{j : key_j > key_i} (keys unique; exact order).
//  2-D grid (i-blocks x j-tiles), atomicAdd partials into pre-zeroed rank. ----
__global__ void __launch_bounds__(256) k_rank(const unsigned long long* __restrict__ sel,
                                              const Hdr* __restrict__ h,
                                              unsigned int* __restrict__ rank){
  __shared__ unsigned long long tile[RANK_JT];
  int n = (int)h->selCount; if (n > SEL_CAP) n = SEL_CAP;
  int j0 = blockIdx.y * RANK_JT;
  if ((int)(blockIdx.x*256) >= n || j0 >= n) return;
  int i = blockIdx.x*256 + threadIdx.x;
  unsigned long long ki = (i < n) ? sel[i] : ~0ULL;   // ~0 counts nothing
  for (int jj = threadIdx.x; jj < RANK_JT; jj += 256)
    tile[jj] = (j0 + jj < n) ? sel[j0 + jj] : 0ULL;   // 0 never > any selected key
  __syncthreads();
  unsigned int c = 0;
  #pragma unroll 8
  for (int j = 0; j < RANK_JT; ++j)
    c += (tile[j] > ki) ? 1u : 0u;
  if (i < n && c) atomicAdd(&rank[i], c);
}

// ---- fused scatter + gather/decode: place item i at output slot rank[i] ----
__global__ void __launch_bounds__(256) k_scatgath(const unsigned long long* __restrict__ sel,
    const Hdr* __restrict__ h, const unsigned int* __restrict__ rank,
    const int* __restrict__ bidx, const int* __restrict__ isz,
    const float4* __restrict__ anc4, const float4* __restrict__ del4,
    float4* __restrict__ boxes, float* __restrict__ areas,
    int* __restrict__ bidxv, int* __restrict__ validv)
{
  int i = blockIdx.x*256 + threadIdx.x;
  int n = (int)h->selCount; if (n > SEL_CAP) n = SEL_CAP;
  if (i >= n) return;
  unsigned int r = rank[i];
  if (r >= N_TOPK) return;
  unsigned long long key = sel[i];
  unsigned int uv = (unsigned int)(key >> 32);
  int idx = (int)(0xFFFFFFFFu - (unsigned int)(key & 0xFFFFFFFFull));
  float4 a = anc4[idx];
  float4 d = del4[idx];
  int b = bidx[idx];
  float H = (float)isz[b*2+0];
  float W = (float)isz[b*2+1];
  float x1,y1,x2,y2; bool valid;
  decode_core(a.x,a.y,a.z,a.w, d.x,d.y,d.z,d.w, H, W, x1,y1,x2,y2, valid);
  boxes[r] = make_float4(x1, y1, x2, y2);
  areas[r] = __fmul_rn(__fsub_rn(x2, x1), __fsub_rn(y2, y1));
  bidxv[r] = b;
  validv[r] = (uv >= 0x80000000u) ? 1 : 0;   // finite score
}

// ---- NMS suppression bitmask: 64x64 tiles, TRANSPOSED write maskT[word][row] ----
__global__ void __launch_bounds__(64) k_mask(const float4* __restrict__ boxes,
                                             const float* __restrict__ areas,
                                             unsigned long long* __restrict__ maskT)
{
  __shared__ float4 cbox[64];
  __shared__ float carea[64];
  int t = threadIdx.x;
  int cb = blockIdx.x, rb = blockIdx.y;
  int r = rb * 64 + t;
  if (cb < rb){                         // strictly below diagonal: all-zero tile
    if (r < N_TOPK) maskT[(size_t)cb * MT_STRIDE + r] = 0ULL;
    return;
  }
  int col0 = cb * 64;
  int c = col0 + t;
  if (c < N_TOPK){ cbox[t] = boxes[c]; carea[t] = areas[c]; }
  __syncthreads();
  if (r >= N_TOPK) return;
  float4 rbx = boxes[r];
  float ra = areas[r];
  unsigned long long m = 0ULL;
  int jmax = N_TOPK - col0; if (jmax > 64) jmax = 64;
  for (int jj = 0; jj < jmax; ++jj){
    int cc = col0 + jj;
    if (cc <= r) continue;
    float4 cbx = cbox[jj];
    float ix1 = fmaxf(rbx.x, cbx.x);
    float iy1 = fmaxf(rbx.y, cbx.y);
    float ix2 = fminf(rbx.z, cbx.z);
    float iy2 = fminf(rbx.w, cbx.w);
    float iw = fmaxf(__fsub_rn(ix2, ix1), 0.0f);
    float ih = fmaxf(__fsub_rn(iy2, iy1), 0.0f);
    float inter = __fmul_rn(iw, ih);
    float denom = __fadd_rn(__fsub_rn(__fadd_rn(ra, carea[jj]), inter), 1e-9f);
    float iou = __fdiv_rn(inter, denom);
    if (iou > NMS_THRESH) m |= (1ULL << jj);
  }
  maskT[(size_t)cb * MT_STRIDE + r] = m;   // coalesced: consecutive r per block
}

// ---- greedy scan, 1 wave, transposed gather ----
__global__ void __launch_bounds__(64) k_scan(const unsigned long long* __restrict__ maskT,
                                             const int* __restrict__ validv,
                                             const float4* __restrict__ boxes,
                                             const int* __restrict__ bidxv,
                                             float* __restrict__ out)
{
  const int lane = threadIdx.x;
  __shared__ int keep[POST_K];
  unsigned long long sA = 0ULL, sB = 0ULL;  // suppressed, transposed: bit k <-> row k*64+lane
  int cnt = 0;
  const int NCHUNK = (N_TOPK + 63) / 64;    // 94
  // prefetch chunk 0 diag + valid
  unsigned long long dvP = maskT[lane];
  bool vbP = validv[lane] != 0;

  for (int c = 0; c < NCHUNK; ++c){
    const int base = c * 64;
    const int nrows = (N_TOPK - base < 64) ? (N_TOPK - base) : 64;
    const unsigned long long rowm = (nrows == 64) ? ~0ULL : ((1ULL << nrows) - 1ULL);
    unsigned long long dv = (lane < nrows) ? dvP : 0ULL;
    bool vb = (lane < nrows) ? vbP : false;
    // gather-OR word c of all alive earlier rows (coalesced, pipelined)
    const unsigned long long* col = maskT + (size_t)c * MT_STRIDE;
    unsigned long long acc = 0ULL;
    {
      int k1 = c < 64 ? c : 64;
      #pragma unroll 4
      for (int k = 0; k < k1; ++k){
        unsigned long long m = col[(k << 6) + lane];
        acc |= m & (((sA >> k) & 1ULL) - 1ULL);   // dead row -> mask 0
      }
      #pragma unroll 4
      for (int k = 64; k < c; ++k){
        unsigned long long m = col[(k << 6) + lane];
        acc |= m & (((sB >> (k - 64)) & 1ULL) - 1ULL);
      }
    }
    #pragma unroll
    for (int d = 1; d < 64; d <<= 1) acc |= __shfl_xor(acc, d);
    const unsigned long long prevw = acc;
    // prefetch next chunk diag + valid (overlaps resolve)
    if (c + 1 < NCHUNK){
      int row2 = base + 64 + lane;
      bool in2 = row2 < N_TOPK;
      dvP = in2 ? maskT[(size_t)(c + 1) * MT_STRIDE + row2] : 0ULL;
      vbP = in2 ? (validv[row2] != 0) : false;
    }
    unsigned long long vmask = __ballot(vb);
    // sequential resolve (wave-uniform; bits at pos i only from rows j<i)
    unsigned long long s = prevw;
    unsigned long long bits = __ballot(dv != 0ULL) & ~prevw;
    while (bits){
      int i = __builtin_ctzll(bits);
      bits &= bits - 1;
      if (((s >> i) & 1ULL) == 0ULL)
        s |= __shfl(dv, i);
    }
    unsigned long long alive = ~s & rowm;
    unsigned long long keepb = alive & vmask;
    if ((keepb >> lane) & 1ULL){
      int pos = cnt + __popcll(keepb & ((1ULL << lane) - 1ULL));
      if (pos < POST_K) keep[pos] = base + lane;
    }
    cnt += (int)__popcll(keepb);
    // record this chunk's suppressed rows into the transposed bitmap
    if ((s >> lane) & 1ULL){
      if (c < 64) sA |= (1ULL << c); else sB |= (1ULL << (c - 64));
    }
    if (cnt >= POST_K || c + 1 == NCHUNK) break;   // wave-uniform
  }
  __syncthreads();
  int kc = cnt > POST_K ? POST_K : cnt;
  for (int cc = lane; cc < POST_K; cc += 64){
    float4 b; float bi;
    if (cc < kc){
      int i = keep[cc];
      b = boxes[i];
      bi = (float)bidxv[i];
    } else {
      b = make_float4(0.f, 0.f, 0.f, 0.f);
      bi = -1.0f;
    }
    out[cc*4+0] = b.x; out[cc*4+1] = b.y; out[cc*4+2] = b.z; out[cc*4+3] = b.w;
    out[POST_K*4 + cc] = bi;
  }
}

extern "C" void kernel_launch(void* const* d_in, const int* in_sizes, int n_in,
                              void* d_out, int out_size, void* d_ws, size_t ws_size,
                              hipStream_t stream)
{
  const int*   bidx   = (const int*)d_in[0];
  const int*   isz    = (const int*)d_in[1];
  const float* anc    = (const float*)d_in[2];
  const float* logits = (const float*)d_in[3];
  const float* delta  = (const float*)d_in[4];
  const int N = in_sizes[0];

  char* ws = (char*)d_ws;
  size_t off = 0;
  unsigned int* u = (unsigned int*)(ws + off);      off += (size_t)N * 4;
  off = (off + 255) & ~(size_t)255;
  Hdr* h = (Hdr*)(ws + off);                        off += sizeof(Hdr);
  off = (off + 255) & ~(size_t)255;
  unsigned long long* sel = (unsigned long long*)(ws + off); off += (size_t)SEL_CAP * 8;
  unsigned int* rank = (unsigned int*)(ws + off);   off += (size_t)SEL_CAP * 4;
  off = (off + 255) & ~(size_t)255;
  float4* boxes = (float4*)(ws + off);              off += (size_t)N_TOPK * 16;
  float*  areas = (float*)(ws + off);               off += (size_t)N_TOPK * 4;
  int*    bidxv = (int*)(ws + off);                 off += (size_t)N_TOPK * 4;
  int*    validv= (int*)(ws + off);                 off += (size_t)N_TOPK * 4;
  off = (off + 255) & ~(size_t)255;
  unsigned long long* maskT = (unsigned long long*)(ws + off); off += (size_t)WORDS * MT_STRIDE * 8;
  (void)ws_size; (void)n_in; (void)out_size;

  float* out = (float*)d_out;

  hipLaunchKernelGGL(k_init,    dim3(64),   dim3(256), 0, stream, h, rank);
  hipLaunchKernelGGL(k_decode,  dim3(2048), dim3(256), 0, stream,
                     bidx, isz, (const float4*)anc, logits, (const float4*)delta, u, N, h);
  hipLaunchKernelGGL(k_pick,    dim3(1),    dim3(256), 0, stream, h, 0);
  hipLaunchKernelGGL(k_hist2,   dim3(1024), dim3(256), 0, stream, (const uint4*)u, N/4, h);
  hipLaunchKernelGGL(k_pick,    dim3(1),    dim3(256), 0, stream, h, 1);
  hipLaunchKernelGGL(k_compact, dim3(256),  dim3(256), 0, stream, (const uint4*)u, N/4, h, sel);
  hipLaunchKernelGGL(k_rank,    dim3(SEL_CAP/256, SEL_CAP/RANK_JT), dim3(256), 0, stream, sel, h, rank);
  hipLaunchKernelGGL(k_scatgath,dim3(SEL_CAP/256), dim3(256), 0, stream,
                     sel, h, rank, bidx, isz, (const float4*)anc, (const float4*)delta,
                     boxes, areas, bidxv, validv);
  hipLaunchKernelGGL(k_mask,    dim3(WORDS, WORDS), dim3(64), 0, stream, boxes, areas, maskT);
  hipLaunchKernelGGL(k_scan,    dim3(1),    dim3(64), 0, stream, maskT, validv, boxes, bidxv, out);
}

// Round 11
// 131.692 us; speedup vs baseline: 1.4232x; 1.4232x over previous
//
#include <hip/hip_runtime.h>
#include <math.h>

#define N_TOPK 6000
#define POST_K 1000
#define WORDS 94            // ceil(6000/64)
#define MT_STRIDE 6016      // padded row count for transposed mask (94*64)
#define SEL_CAP 16384       // n ~= 6002 with 25-bit threshold; big headroom
#define RANK_JT 1024
#define NMS_THRESH 0.7f
#define HPAD 16             // one counter per 64B cacheline (Hdr hists)
#define NBIN1 4096          // level-1: top 12 bits
#define BSHIFT1 20
#define NBIN2 8192          // level-2: next 13 bits
#define BSHIFT2 7
#define NREP 32             // flush replicas (packed, no HPAD)
#define INV_KEY 0x007FFFFFu // monotone key of -inf score
#define INV_BIN (INV_KEY >> BSHIFT1)   // = 7

struct Hdr {
  unsigned int hist1[NBIN1*HPAD];
  unsigned int hist2[NBIN2*HPAD];
  unsigned int binB;             // pick1: top-12-bit boundary bin
  unsigned int kth;              // remaining rank within bin B
  unsigned int thr;              // pick2: 25-bit selection threshold
  unsigned int selCount;
};

// ---- shared decode core (must match reference numerics; _rn blocks FMA) ----
__device__ __forceinline__ void decode_core(
    float a0, float a1, float a2, float a3,
    float d0, float d1, float d2, float d3,
    float H, float W,
    float& x1, float& y1, float& x2, float& y2, bool& valid)
{
  float aw = __fsub_rn(a2, a0);
  float ah = __fsub_rn(a3, a1);
  float ax = __fadd_rn(a0, __fmul_rn(0.5f, aw));
  float ay = __fadd_rn(a1, __fmul_rn(0.5f, ah));
  float px = __fadd_rn(ax, __fmul_rn(d0, aw));
  float py = __fadd_rn(ay, __fmul_rn(d1, ah));
  float c2 = fminf(fmaxf(d2, -10.0f), 10.0f);
  float c3 = fminf(fmaxf(d3, -10.0f), 10.0f);
  // correctly-rounded f32 exp via double (central w.r.t. any 1-ulp reference exp)
  float pw = __fmul_rn(aw, (float)exp((double)c2));
  float ph = __fmul_rn(ah, (float)exp((double)c3));
  float Wm = __fsub_rn(W, 1.0f);
  float Hm = __fsub_rn(H, 1.0f);
  float hw = __fmul_rn(0.5f, pw);
  float hh = __fmul_rn(0.5f, ph);
  x1 = fminf(fmaxf(__fsub_rn(px, hw), 0.0f), Wm);
  y1 = fminf(fmaxf(__fsub_rn(py, hh), 0.0f), Hm);
  x2 = fminf(fmaxf(__fadd_rn(px, hw), 0.0f), Wm);
  y2 = fminf(fmaxf(__fadd_rn(py, hh), 0.0f), Hm);
  valid = (__fsub_rn(x2, x1) >= 16.0f) && (__fsub_rn(y2, y1) >= 16.0f);
}

// ---- init: zero hist2 / rep / rank / counters ----
__global__ void __launch_bounds__(256) k_init(Hdr* h, unsigned int* rep, unsigned int* rank){
  int tid = blockIdx.x*256 + threadIdx.x;
  int stride = gridDim.x*256;
  for (int i = tid; i < NBIN2*HPAD; i += stride) h->hist2[i] = 0;
  for (int i = tid; i < NREP*NBIN1; i += stride) rep[i] = 0;
  for (int i = tid; i < SEL_CAP; i += stride) rank[i] = 0;
  if (tid == 0){ h->binB = 0; h->kth = 0; h->thr = 0; h->selCount = 0; }
}

// ---- stage 1: decode + score -> monotone u32 key; 12-bit LDS histogram.
//  Invalid elements counted in a register (all map to one bin -> would
//  serialize the DS atomic unit); flush goes to packed replicas so the
//  same-address global-atomic depth is grid/NREP, not grid (R10 lesson). ----
__global__ void __launch_bounds__(256) k_decode(const int* __restrict__ bidx,
    const int* __restrict__ isz, const float4* __restrict__ anc4,
    const float* __restrict__ logits, const float4* __restrict__ del4,
    unsigned int* __restrict__ u, int N, unsigned int* __restrict__ rep)
{
  __shared__ unsigned int lh[NBIN1];
  for (int b = threadIdx.x; b < NBIN1; b += 256) lh[b] = 0;
  __syncthreads();
  int stride = gridDim.x*blockDim.x;
  unsigned int invLocal = 0;
  for (int i = blockIdx.x*blockDim.x + threadIdx.x; i < N; i += stride){
    float4 a = anc4[i];
    float4 d = del4[i];
    int b = bidx[i];
    float H = (float)isz[b*2+0];
    float W = (float)isz[b*2+1];
    float x1,y1,x2,y2; bool valid;
    decode_core(a.x,a.y,a.z,a.w, d.x,d.y,d.z,d.w, H, W, x1,y1,x2,y2, valid);
    if (valid){
      float x = logits[i];
      float e = (float)exp(-(double)x);           // exp-form sigmoid (XLA logistic expander)
      float s = __fdiv_rn(1.0f, __fadd_rn(1.0f, e));
      unsigned int w = __float_as_uint(s);
      unsigned int key = (w & 0x80000000u) ? ~w : (w | 0x80000000u);
      u[i] = key;
      atomicAdd(&lh[key >> BSHIFT1], 1u);
    } else {
      u[i] = INV_KEY;
      invLocal++;
    }
  }
  if (invLocal) atomicAdd(&lh[INV_BIN], invLocal);
  __syncthreads();
  unsigned int* myrep = rep + (size_t)(blockIdx.x & (NREP-1)) * NBIN1;
  for (int b = threadIdx.x; b < NBIN1; b += 256){
    unsigned int c = lh[b];
    if (c) atomicAdd(&myrep[b], c);
  }
}

// ---- sum replicas -> hist1 (plain stores; no atomics) ----
__global__ void __launch_bounds__(256) k_reduce(const unsigned int* __restrict__ rep,
                                                Hdr* __restrict__ h){
  int bin = blockIdx.x*256 + threadIdx.x;   // grid = NBIN1/256
  unsigned int s = 0;
  #pragma unroll
  for (int r = 0; r < NREP; ++r) s += rep[(size_t)r*NBIN1 + bin];
  h->hist1[(size_t)bin*HPAD] = s;
}

// ---- pick1 over 4096 bins: boundary bin B + remaining rank kth ----
__global__ void __launch_bounds__(256) k_pick1(Hdr* h){
  __shared__ unsigned int A[256];
  const int t = threadIdx.x;
  unsigned int loc[16];
  unsigned int L = 0;
  #pragma unroll
  for (int r = 0; r < 16; ++r){
    loc[r] = h->hist1[(size_t)(t*16 + r)*HPAD];
    L += loc[r];
  }
  A[t] = L;
  __syncthreads();
  for (int d = 1; d < 256; d <<= 1){
    unsigned int v = A[t];
    if (t + d < 256) v += A[t + d];
    __syncthreads();
    A[t] = v;
    __syncthreads();
  }
  unsigned int suf = A[t];
  unsigned int sufNext = (t < 255) ? A[t+1] : 0;
  if (suf >= N_TOPK && sufNext < N_TOPK){   // exactly one thread
    unsigned int acc = sufNext;
    int bb = t*16;
    #pragma unroll
    for (int r = 15; r >= 0; --r){
      acc += loc[r];
      if (acc >= N_TOPK){ bb = t*16 + r; acc -= loc[r]; break; }
    }
    h->binB = (unsigned int)bb;
    h->kth = N_TOPK - acc;     // remaining rank within bin bb
  }
}

// ---- second-level histogram: keys in bin B, bits 19..7 ----
__global__ void __launch_bounds__(256) k_hist2(const uint4* __restrict__ u4, int N4,
                                               Hdr* __restrict__ h){
  unsigned int B = h->binB;
  int stride = gridDim.x*blockDim.x;
  for (int i = blockIdx.x*blockDim.x + threadIdx.x; i < N4; i += stride){
    uint4 v = u4[i];
    #pragma unroll
    for (int kcomp = 0; kcomp < 4; ++kcomp){
      unsigned int vv = (kcomp==0)?v.x:(kcomp==1)?v.y:(kcomp==2)?v.z:v.w;
      if ((vv >> BSHIFT1) == B)
        atomicAdd(&h->hist2[(size_t)((vv >> BSHIFT2) & (NBIN2-1))*HPAD], 1u);
    }
  }
}

// ---- pick2 over 8192 sub-bins: thr = (B<<20)|(S<<7) ----
__global__ void __launch_bounds__(256) k_pick2(Hdr* h){
  __shared__ unsigned int A[256];
  const int t = threadIdx.x;
  unsigned int target = h->kth;
  unsigned int loc[32];
  unsigned int L = 0;
  #pragma unroll
  for (int r = 0; r < 32; ++r){
    loc[r] = h->hist2[(size_t)(t*32 + r)*HPAD];
    L += loc[r];
  }
  A[t] = L;
  __syncthreads();
  for (int d = 1; d < 256; d <<= 1){
    unsigned int v = A[t];
    if (t + d < 256) v += A[t + d];
    __syncthreads();
    A[t] = v;
    __syncthreads();
  }
  unsigned int suf = A[t];
  unsigned int sufNext = (t < 255) ? A[t+1] : 0;
  if (suf >= target && sufNext < target){   // exactly one thread
    unsigned int acc = sufNext;
    int bb = t*32;
    #pragma unroll
    for (int r = 31; r >= 0; --r){
      acc += loc[r];
      if (acc >= target){ bb = t*32 + r; break; }
    }
    h->thr = (h->binB << BSHIFT1) | ((unsigned int)bb << BSHIFT2);
  }
}

// ---- compact all u >= thr (n ~= 6002 << SEL_CAP); block-aggregated allocation ----
__global__ void __launch_bounds__(256) k_compact(const uint4* __restrict__ u4, int N4,
                                                 Hdr* __restrict__ h,
                                                 unsigned long long* __restrict__ sel){
  __shared__ unsigned long long lbuf[1024];
  __shared__ unsigned int lcnt, lbase;
  if (threadIdx.x == 0) lcnt = 0;
  __syncthreads();
  unsigned int thr = h->thr;
  int stride = gridDim.x*blockDim.x;
  for (int i = blockIdx.x*blockDim.x + threadIdx.x; i < N4; i += stride){
    uint4 v = u4[i];
    unsigned int base = (unsigned int)i * 4u;
    #pragma unroll
    for (int kcomp = 0; kcomp < 4; ++kcomp){
      unsigned int vv = (kcomp==0)?v.x:(kcomp==1)?v.y:(kcomp==2)?v.z:v.w;
      if (vv >= thr){
        unsigned long long key = ((unsigned long long)vv << 32)
                               | (unsigned long long)(0xFFFFFFFFu - (base + kcomp));
        unsigned int p = atomicAdd(&lcnt, 1u);
        if (p < 1024){
          lbuf[p] = key;
        } else {                                   // overflow fallback
          unsigned int gp = atomicAdd(&h->selCount, 1u);
          if (gp < SEL_CAP) sel[gp] = key;
        }
      }
    }
  }
  __syncthreads();
  unsigned int n = lcnt; if (n > 1024) n = 1024;
  if (threadIdx.x == 0 && n) lbase = atomicAdd(&h->selCount, n);
  __syncthreads();
  if (n){
    unsigned int base = lbase;
    for (unsigned int kk = threadIdx.x; kk < n; kk += 256){
      unsigned int p = base + kk;
      if (p < SEL_CAP) sel[p] = lbuf[kk];
    }
  }
}

// ---- rank: rank_i = #{j : key_j > key_i} (keys unique; exact order) ----
__global__ void __launch_bounds__(256) k_rank(const unsigned long long* __restrict__ sel,
                                              const Hdr* __restrict__ h,
                                              unsigned int* __restrict__ rank){
  __shared__ unsigned long long tile[RANK_JT];
  int n = (int)h->selCount; if (n > SEL_CAP) n = SEL_CAP;
  int j0 = blockIdx.y * RANK_JT;
  if ((int)(blockIdx.x*256) >= n || j0 >= n) return;
  int i = blockIdx.x*256 + threadIdx.x;
  unsigned long long ki = (i < n) ? sel[i] : ~0ULL;   // ~0 counts nothing
  for (int jj = threadIdx.x; jj < RANK_JT; jj += 256)
    tile[jj] = (j0 + jj < n) ? sel[j0 + jj] : 0ULL;   // 0 never > any selected key
  __syncthreads();
  unsigned int c = 0;
  #pragma unroll 8
  for (int j = 0; j < RANK_JT; ++j)
    c += (tile[j] > ki) ? 1u : 0u;
  if (i < n && c) atomicAdd(&rank[i], c);
}

// ---- fused scatter + gather/decode: place item i at output slot rank[i] ----
__global__ void __launch_bounds__(256) k_scatgath(const unsigned long long* __restrict__ sel,
    const Hdr* __restrict__ h, const unsigned int* __restrict__ rank,
    const int* __restrict__ bidx, const int* __restrict__ isz,
    const float4* __restrict__ anc4, const float4* __restrict__ del4,
    float4* __restrict__ boxes, float* __restrict__ areas,
    int* __restrict__ bidxv, int* __restrict__ validv)
{
  int i = blockIdx.x*256 + threadIdx.x;
  int n = (int)h->selCount; if (n > SEL_CAP) n = SEL_CAP;
  if (i >= n) return;
  unsigned int r = rank[i];
  if (r >= N_TOPK) return;
  unsigned long long key = sel[i];
  unsigned int uv = (unsigned int)(key >> 32);
  int idx = (int)(0xFFFFFFFFu - (unsigned int)(key & 0xFFFFFFFFull));
  float4 a = anc4[idx];
  float4 d = del4[idx];
  int b = bidx[idx];
  float H = (float)isz[b*2+0];
  float W = (float)isz[b*2+1];
  float x1,y1,x2,y2; bool valid;
  decode_core(a.x,a.y,a.z,a.w, d.x,d.y,d.z,d.w, H, W, x1,y1,x2,y2, valid);
  boxes[r] = make_float4(x1, y1, x2, y2);
  areas[r] = __fmul_rn(__fsub_rn(x2, x1), __fsub_rn(y2, y1));
  bidxv[r] = b;
  validv[r] = (uv >= 0x80000000u) ? 1 : 0;   // finite score
}

// ---- NMS suppression bitmask: 64x64 tiles, TRANSPOSED write maskT[word][row] ----
__global__ void __launch_bounds__(64) k_mask(const float4* __restrict__ boxes,
                                             const float* __restrict__ areas,
                                             unsigned long long* __restrict__ maskT)
{
  __shared__ float4 cbox[64];
  __shared__ float carea[64];
  int t = threadIdx.x;
  int cb = blockIdx.x, rb = blockIdx.y;
  int r = rb * 64 + t;
  if (cb < rb){                         // strictly below diagonal: all-zero tile
    if (r < N_TOPK) maskT[(size_t)cb * MT_STRIDE + r] = 0ULL;
    return;
  }
  int col0 = cb * 64;
  int c = col0 + t;
  if (c < N_TOPK){ cbox[t] = boxes[c]; carea[t] = areas[c]; }
  __syncthreads();
  if (r >= N_TOPK) return;
  float4 rbx = boxes[r];
  float ra = areas[r];
  unsigned long long m = 0ULL;
  int jmax = N_TOPK - col0; if (jmax > 64) jmax = 64;
  for (int jj = 0; jj < jmax; ++jj){
    int cc = col0 + jj;
    if (cc <= r) continue;
    float4 cbx = cbox[jj];
    float ix1 = fmaxf(rbx.x, cbx.x);
    float iy1 = fmaxf(rbx.y, cbx.y);
    float ix2 = fminf(rbx.z, cbx.z);
    float iy2 = fminf(rbx.w, cbx.w);
    float iw = fmaxf(__fsub_rn(ix2, ix1), 0.0f);
    float ih = fmaxf(__fsub_rn(iy2, iy1), 0.0f);
    float inter = __fmul_rn(iw, ih);
    float denom = __fadd_rn(__fsub_rn(__fadd_rn(ra, carea[jj]), inter), 1e-9f);
    float iou = __fdiv_rn(inter, denom);
    if (iou > NMS_THRESH) m |= (1ULL << jj);
  }
  maskT[(size_t)cb * MT_STRIDE + r] = m;   // coalesced: consecutive r per block
}

// ---- greedy scan, 1 wave, transposed gather ----
__global__ void __launch_bounds__(64) k_scan(const unsigned long long* __restrict__ maskT,
                                             const int* __restrict__ validv,
                                             const float4* __restrict__ boxes,
                                             const int* __restrict__ bidxv,
                                             float* __restrict__ out)
{
  const int lane = threadIdx.x;
  __shared__ int keep[POST_K];
  unsigned long long sA = 0ULL, sB = 0ULL;  // suppressed, transposed: bit k <-> row k*64+lane
  int cnt = 0;
  const int NCHUNK = (N_TOPK + 63) / 64;    // 94
  unsigned long long dvP = maskT[lane];
  bool vbP = validv[lane] != 0;

  for (int c = 0; c < NCHUNK; ++c){
    const int base = c * 64;
    const int nrows = (N_TOPK - base < 64) ? (N_TOPK - base) : 64;
    const unsigned long long rowm = (nrows == 64) ? ~0ULL : ((1ULL << nrows) - 1ULL);
    unsigned long long dv = (lane < nrows) ? dvP : 0ULL;
    bool vb = (lane < nrows) ? vbP : false;
    // gather-OR word c of all alive earlier rows (coalesced, pipelined)
    const unsigned long long* col = maskT + (size_t)c * MT_STRIDE;
    unsigned long long acc = 0ULL;
    {
      int k1 = c < 64 ? c : 64;
      #pragma unroll 4
      for (int k = 0; k < k1; ++k){
        unsigned long long m = col[(k << 6) + lane];
        acc |= m & (((sA >> k) & 1ULL) - 1ULL);   // dead row -> mask 0
      }
      #pragma unroll 4
      for (int k = 64; k < c; ++k){
        unsigned long long m = col[(k << 6) + lane];
        acc |= m & (((sB >> (k - 64)) & 1ULL) - 1ULL);
      }
    }
    #pragma unroll
    for (int d = 1; d < 64; d <<= 1) acc |= __shfl_xor(acc, d);
    const unsigned long long prevw = acc;
    if (c + 1 < NCHUNK){
      int row2 = base + 64 + lane;
      bool in2 = row2 < N_TOPK;
      dvP = in2 ? maskT[(size_t)(c + 1) * MT_STRIDE + row2] : 0ULL;
      vbP = in2 ? (validv[row2] != 0) : false;
    }
    unsigned long long vmask = __ballot(vb);
    unsigned long long s = prevw;
    unsigned long long bits = __ballot(dv != 0ULL) & ~prevw;
    while (bits){
      int i = __builtin_ctzll(bits);
      bits &= bits - 1;
      if (((s >> i) & 1ULL) == 0ULL)
        s |= __shfl(dv, i);
    }
    unsigned long long alive = ~s & rowm;
    unsigned long long keepb = alive & vmask;
    if ((keepb >> lane) & 1ULL){
      int pos = cnt + __popcll(keepb & ((1ULL << lane) - 1ULL));
      if (pos < POST_K) keep[pos] = base + lane;
    }
    cnt += (int)__popcll(keepb);
    if ((s >> lane) & 1ULL){
      if (c < 64) sA |= (1ULL << c); else sB |= (1ULL << (c - 64));
    }
    if (cnt >= POST_K || c + 1 == NCHUNK) break;   // wave-uniform
  }
  __syncthreads();
  int kc = cnt > POST_K ? POST_K : cnt;
  for (int cc = lane; cc < POST_K; cc += 64){
    float4 b; float bi;
    if (cc < kc){
      int i = keep[cc];
      b = boxes[i];
      bi = (float)bidxv[i];
    } else {
      b = make_float4(0.f, 0.f, 0.f, 0.f);
      bi = -1.0f;
    }
    out[cc*4+0] = b.x; out[cc*4+1] = b.y; out[cc*4+2] = b.z; out[cc*4+3] = b.w;
    out[POST_K*4 + cc] = bi;
  }
}

extern "C" void kernel_launch(void* const* d_in, const int* in_sizes, int n_in,
                              void* d_out, int out_size, void* d_ws, size_t ws_size,
                              hipStream_t stream)
{
  const int*   bidx   = (const int*)d_in[0];
  const int*   isz    = (const int*)d_in[1];
  const float* anc    = (const float*)d_in[2];
  const float* logits = (const float*)d_in[3];
  const float* delta  = (const float*)d_in[4];
  const int N = in_sizes[0];

  char* ws = (char*)d_ws;
  size_t off = 0;
  unsigned int* u = (unsigned int*)(ws + off);      off += (size_t)N * 4;
  off = (off + 255) & ~(size_t)255;
  Hdr* h = (Hdr*)(ws + off);                        off += sizeof(Hdr);
  off = (off + 255) & ~(size_t)255;
  unsigned int* rep = (unsigned int*)(ws + off);    off += (size_t)NREP * NBIN1 * 4;
  off = (off + 255) & ~(size_t)255;
  unsigned long long* sel = (unsigned long long*)(ws + off); off += (size_t)SEL_CAP * 8;
  unsigned int* rank = (unsigned int*)(ws + off);   off += (size_t)SEL_CAP * 4;
  off = (off + 255) & ~(size_t)255;
  float4* boxes = (float4*)(ws + off);              off += (size_t)N_TOPK * 16;
  float*  areas = (float*)(ws + off);               off += (size_t)N_TOPK * 4;
  int*    bidxv = (int*)(ws + off);                 off += (size_t)N_TOPK * 4;
  int*    validv= (int*)(ws + off);                 off += (size_t)N_TOPK * 4;
  off = (off + 255) & ~(size_t)255;
  unsigned long long* maskT = (unsigned long long*)(ws + off); off += (size_t)WORDS * MT_STRIDE * 8;
  (void)ws_size; (void)n_in; (void)out_size;

  float* out = (float*)d_out;

  hipLaunchKernelGGL(k_init,    dim3(64),   dim3(256), 0, stream, h, rep, rank);
  hipLaunchKernelGGL(k_decode,  dim3(2048), dim3(256), 0, stream,
                     bidx, isz, (const float4*)anc, logits, (const float4*)delta, u, N, rep);
  hipLaunchKernelGGL(k_reduce,  dim3(NBIN1/256), dim3(256), 0, stream, rep, h);
  hipLaunchKernelGGL(k_pick1,   dim3(1),    dim3(256), 0, stream, h);
  hipLaunchKernelGGL(k_hist2,   dim3(1024), dim3(256), 0, stream, (const uint4*)u, N/4, h);
  hipLaunchKernelGGL(k_pick2,   dim3(1),    dim3(256), 0, stream, h);
  hipLaunchKernelGGL(k_compact, dim3(256),  dim3(256), 0, stream, (const uint4*)u, N/4, h, sel);
  hipLaunchKernelGGL(k_rank,    dim3(SEL_CAP/256, SEL_CAP/RANK_JT), dim3(256), 0, stream, sel, h, rank);
  hipLaunchKernelGGL(k_scatgath,dim3(SEL_CAP/256), dim3(256), 0, stream,
                     sel, h, rank, bidx, isz, (const float4*)anc, (const float4*)delta,
                     boxes, areas, bidxv, validv);
  hipLaunchKernelGGL(k_mask,    dim3(WORDS, WORDS), dim3(64), 0, stream, boxes, areas, maskT);
  hipLaunchKernelGGL(k_scan,    dim3(1),    dim3(64), 0, stream, maskT, validv, boxes, bidxv, out);
}